// Round 7
// baseline (1427.536 us; speedup 1.0000x reference)
//
#include <hip/hip_runtime.h>
#include <hip/hip_bf16.h>

// LSTM H=1024, B=256, T=256, C=10 — round 18.
// Rounds 17/17b (L2-resident flags) killed the container twice — same death
// mode as round 12. Traced terminal race: consumer flag lines are evicted
// from the XCD L2 by the 4MB/step frag stream; IC refetch can be served by
// stale cross-launch dirty-line evictions; if the producer already finished,
// no rewrite heals it -> infinite spin -> GPU wedge. L2 flags are abandoned.
// Round 18 = round 16 (PROVEN, 1087us) + ONE safe publish-path cut, flag
// memory path (IC, sc1, memset-reset) byte-identical:
//  - PER-WAVE flags: wave w drains its own h-stores (vmcnt(0)) and stores
//    flags[bid*32+w] = t+1 BEFORE the second barrier. Removes the barrier
//    join + tid0 hop from the publish path (~200-500 cy/step).
//  - consumer polls all 8 wave-words of each producer line: producer =
//    lane>>3, word = lane&7 (64 distinct words, same traffic as before).
//  - soundness as r16: consumer proceeds only after all 8 waves of all 8
//    producers drained; WAR gate still the pre-MFMA union poll + barrier;
//    memset 0 < all targets (t+1 >= 1).
// Prediction: dur -> ~1030-1070 if publish path is on the chain; flat ->
// publish exonerated -> pivot to stamped-data single-trip protocol.
// WRITE_SIZE may rise to <=33MB (8 flag lines vs 1) — harmless.

#define H 1024
#define B 256
#define T 256
#define NCLS 10

typedef __attribute__((ext_vector_type(8))) short short8;   // 8 bf16
typedef __attribute__((ext_vector_type(2))) float f32x2;
typedef __attribute__((ext_vector_type(4))) float f32x4;
typedef __attribute__((ext_vector_type(16))) float f32x16;

__device__ inline unsigned short bf16_bits(float f) {
    union { __hip_bfloat16 h; unsigned short u; } cv;
    cv.h = __float2bfloat16(f);
    return cv.u;
}

#define L2E 1.4426950408889634f
__device__ inline float sigm_fast(float x) {
    float e = __builtin_amdgcn_exp2f(-L2E * x);
    return __builtin_amdgcn_rcpf(1.0f + e);
}
__device__ inline float tanh_fast(float x) {
    float e = __builtin_amdgcn_exp2f((2.0f * L2E) * x);     // e^(2x)
    return 1.0f - 2.0f * __builtin_amdgcn_rcpf(1.0f + e);   // +-sat correct
}

// h frag layout (per 512 KB buffer), 32x32x16 B-frag order, per bt-slice:
//   short index of (j in [0,1024), b-in-slice nn in [0,32)):
//   bt*32768 + (j>>4)*512 + ((j>>3)&1)*256 + nn*8 + (j&7)
// Wave kq's quarter = bytes [kq*16384, +16384) of the bt-slice; kstep c at
// byte kq*16384 + c*1024 + lane*16 == the 32x32x16 B-frag for that kstep.

#define LOADS4(d0, d1, d2, d3, PTR, SC)                                   \
    __asm__ volatile(                                                     \
        "global_load_dwordx4 %0, %4, off " SC "\n\t"                      \
        "global_load_dwordx4 %1, %4, off offset:1024 " SC "\n\t"          \
        "global_load_dwordx4 %2, %4, off offset:2048 " SC "\n\t"          \
        "global_load_dwordx4 %3, %4, off offset:3072 " SC                  \
        : "=&v"(d0), "=&v"(d1), "=&v"(d2), "=&v"(d3)                      \
        : "v"(PTR));

#define WAIT4(N, d0, d1, d2, d3)                                          \
    __asm__ volatile("s_waitcnt vmcnt(" N ")"                             \
        : "+v"(d0), "+v"(d1), "+v"(d2), "+v"(d3));

#define MM(c, bb)                                                         \
    acc0 = __builtin_amdgcn_mfma_f32_32x32x16_bf16(awreg[0][c], bb, acc0, 0, 0, 0); \
    acc1 = __builtin_amdgcn_mfma_f32_32x32x16_bf16(awreg[1][c], bb, acc1, 0, 0, 0);

#define GATE_MFMA(SC)                                                     \
    {                                                                     \
        short8 b0, b1, b2, b3, b4, b5, b6, b7;                            \
        short8 b8, b9, b10, b11, b12, b13, b14, b15;                      \
        LOADS4(b0, b1, b2, b3, gb, SC)                                    \
        LOADS4(b4, b5, b6, b7, gb + 4096, SC)                             \
        WAIT4("4", b0, b1, b2, b3)                                        \
        MM(0, b0) MM(1, b1) MM(2, b2) MM(3, b3)                           \
        LOADS4(b8, b9, b10, b11, gb + 8192, SC)                           \
        LOADS4(b12, b13, b14, b15, gb + 12288, SC)                        \
        WAIT4("8", b4, b5, b6, b7)                                        \
        MM(4, b4) MM(5, b5) MM(6, b6) MM(7, b7)                           \
        WAIT4("4", b8, b9, b10, b11)                                      \
        MM(8, b8) MM(9, b9) MM(10, b10) MM(11, b11)                       \
        WAIT4("0", b12, b13, b14, b15)                                    \
        MM(12, b12) MM(13, b13) MM(14, b14) MM(15, b15)                   \
    }

__global__ __launch_bounds__(512)
__attribute__((amdgpu_waves_per_eu(2, 2)))
void lstm_persist(
    const float* __restrict__ x,
    const float* __restrict__ Wgh, const float* __restrict__ Wih,
    const float* __restrict__ Wfh, const float* __restrict__ Woh,
    const float* __restrict__ Wgx, const float* __restrict__ Wix,
    const float* __restrict__ Wfx, const float* __restrict__ Wox,
    const float* __restrict__ bg, const float* __restrict__ bi,
    const float* __restrict__ bf_, const float* __restrict__ bo,
    char* __restrict__ frag,            // 2 x 524288 bytes (NOT pre-zeroed)
    unsigned* __restrict__ flags,       // 256 lines x 128 B; words 0..7 used
    unsigned* __restrict__ det,         // 256 slots x 4B (IC), zeroed
    float* __restrict__ hfin)           // H x B fp32
{
    __shared__ __align__(16) float zb[16][32][32]; // [kq*4+g][col][swz rows]
    __shared__ float wxl[4][32];
    __shared__ float bsl[4][32];
    __shared__ int sh_lcl;

    const int tid  = threadIdx.x;
    const int lane = tid & 63;
    const int wave = tid >> 6;          // 0..7
    const int gp   = wave >> 2;         // gate pair: 0 -> {g,i}, 1 -> {f,o}
    const int kq   = wave & 3;          // k-quarter (256 of K=1024)
    const int bt = blockIdx.x & 7;      // work mapping == round 11 (unchanged)
    const int jt = blockIdx.x >> 3;
    const int j0 = jt * 32;
    const int b0 = bt * 32;

    // ---- one-time: publish my physical XCD id to my group's det slot ----
    unsigned xcc;
    __asm__ volatile("s_getreg_b32 %0, hwreg(HW_REG_XCC_ID)" : "=s"(xcc));
    xcc &= 7u;
    if (tid == 0)
        __hip_atomic_store(&det[bt * 32 + jt], xcc + 1u,
                           __ATOMIC_RELAXED, __HIP_MEMORY_SCOPE_AGENT);

    if (tid < 128) {
        int g = tid >> 5, r = tid & 31;
        const float* wx = (g == 0) ? Wgx : (g == 1) ? Wix : (g == 2) ? Wfx : Wox;
        const float* bb = (g == 0) ? bg  : (g == 1) ? bi  : (g == 2) ? bf_ : bo;
        wxl[g][r] = wx[j0 + r];
        bsl[g][r] = bb[b0 + r];
    }

    // ---- one-time: W tiles -> registers, 32x32x16 A-fragment order ----
    // (verified by round-14 pass): row = lane&31, k = (lane>>5)*8 + e.
    const float* Wlo = (gp == 0) ? Wgh : Wfh;
    const float* Whi = (gp == 0) ? Wih : Woh;
    short8 awreg[2][16];
#pragma unroll
    for (int gg = 0; gg < 2; ++gg) {
        const float* Wp = gg ? Whi : Wlo;
        const float* wrow = Wp + (j0 + (lane & 31)) * H
                          + kq * 256 + ((lane >> 5) * 8);
#pragma unroll
        for (int c = 0; c < 16; ++c) {
            const float4 f0 = *(const float4*)(wrow + c * 16);
            const float4 f1 = *(const float4*)(wrow + c * 16 + 4);
            short8 s;
            s[0] = (short)bf16_bits(f0.x); s[1] = (short)bf16_bits(f0.y);
            s[2] = (short)bf16_bits(f0.z); s[3] = (short)bf16_bits(f0.w);
            s[4] = (short)bf16_bits(f1.x); s[5] = (short)bf16_bits(f1.y);
            s[6] = (short)bf16_bits(f1.z); s[7] = (short)bf16_bits(f1.w);
            awreg[gg][c] = s;
        }
    }
#pragma unroll
    for (int gg = 0; gg < 2; ++gg)
#pragma unroll
        for (int c = 0; c < 16; ++c)
            __asm__ volatile("" : "+a"(awreg[gg][c]));

    // ---- one-time: group locality verdict (poll my group's 32 det slots) ----
    if (wave == 0) {
        unsigned v;
        while (true) {
            v = __hip_atomic_load(&det[bt * 32 + (lane & 31)],
                                  __ATOMIC_RELAXED, __HIP_MEMORY_SCOPE_AGENT);
            if (__all((int)(v != 0u))) break;
            __builtin_amdgcn_s_sleep(1);
        }
        int same = __all((int)(v == xcc + 1u));
        if (tid == 0) sh_lcl = same;
    }
    __syncthreads();
    const bool lcl = (sh_lcl != 0);

    float creg[2] = {0.f, 0.f};
    const int nn = tid & 31;
    const int aa = tid >> 5;            // 0..15: rows 2aa, 2aa+1

    // per-wave arrive flag: word `wave` of my block's 128-B line
    unsigned* myflag = &flags[blockIdx.x * 32 + wave];
    // per-wave poll set: 8 producers (lane>>3) x 8 wave-words (lane&7)
    unsigned* pollflag = &flags[(((kq << 3) + (lane >> 3)) * 8 + bt) * 32
                                + (lane & 7)];

    for (int t = 0; t < T; ++t) {
        const float xv = x[(b0 + nn) * T + t];

        f32x16 acc0 = {0.f,0.f,0.f,0.f,0.f,0.f,0.f,0.f,
                       0.f,0.f,0.f,0.f,0.f,0.f,0.f,0.f};
        f32x16 acc1 = acc0;

        if (t > 0) {        // h_0 == 0 -> z == 0: skip poll+loads+MFMA at t=0
            // ---- per-wave wait: all 8 waves of my 8 producers >= t ----
            {
                const unsigned target = (unsigned)t;
                while (true) {
                    unsigned v = __hip_atomic_load(pollflag, __ATOMIC_RELAXED,
                                                   __HIP_MEMORY_SCOPE_AGENT);
                    if (__all((int)(v >= target))) break;
                    __builtin_amdgcn_s_sleep(1);
                }
            }
            // force xv retired so vmcnt counts below are exact
            __asm__ volatile("" :: "v"(xv));

            // ---- B-frags direct from global, counted-vmcnt MFMA ----
            const char* gb = frag + (t & 1) * 524288 + bt * 65536
                           + (kq << 14) + lane * 16;
            if (lcl) {       // XCD-local exchange: L2 hit (L1 bypass only)
                GATE_MFMA("sc0")
            } else {         // cross-XCD: IC path (round-11 semantics)
                GATE_MFMA("sc0 sc1")
            }
        }

        // C/D (HW-verified 32x32): col = lane&31,
        // row = (reg&3) + 8*(reg>>2) + 4*(lane>>5) = 4*grp + e, grp=2*rq+hi.
        // zb float idx: ((kq*4+g)<<10) + (col<<5) + ((grp^(col&7))<<2) + e.
        {
            float* zbF = &zb[0][0][0];
            const int col = lane & 31;
            const int hi  = lane >> 5;
            const int g0 = gp * 2, g1 = g0 + 1;
#pragma unroll
            for (int rq = 0; rq < 4; ++rq) {
                const int sw = ((2 * rq + hi) ^ (col & 7)) << 2;
                f32x4 w0, w1;
#pragma unroll
                for (int e = 0; e < 4; ++e) {
                    w0[e] = acc0[rq * 4 + e];
                    w1[e] = acc1[rq * 4 + e];
                }
                *(f32x4*)(zbF + ((kq * 4 + g0) << 10) + (col << 5) + sw) = w0;
                *(f32x4*)(zbF + ((kq * 4 + g1) << 10) + (col << 5) + sw) = w1;
            }
        }
        __syncthreads();   // all waves' polls done => all 32 peers >= t:
                           // stores below cannot overwrite a peer's live read

        // ---- elementwise epilogue: 512 threads x 2 rows (f32x2 zb reads) ----
        {
            const int grp = aa >> 1, half = aa & 1;  // rows 4grp+2half+{0,1}
            const float* zcol = &zb[0][0][0] + (nn << 5);
            const int fo = ((grp ^ (nn & 7)) << 2) + (half << 1);
            f32x2 zs[4];
#pragma unroll
            for (int gi = 0; gi < 4; ++gi) {
                f32x2 s = *(const f32x2*)(zcol + (gi << 10) + fo);
#pragma unroll
                for (int kk = 1; kk < 4; ++kk)
                    s += *(const f32x2*)(zcol + (((kk << 2) + gi) << 10) + fo);
                zs[gi] = s;
            }
            unsigned short hb[2];
#pragma unroll
            for (int q = 0; q < 2; ++q) {
                const int jl = 2 * aa + q;
                float zg = zs[0][q] + wxl[0][jl] * xv + bsl[0][nn];
                float zi = zs[1][q] + wxl[1][jl] * xv + bsl[1][nn];
                float zf = zs[2][q] + wxl[2][jl] * xv + bsl[2][nn];
                float zo = zs[3][q] + wxl[3][jl] * xv + bsl[3][nn];
                float g  = tanh_fast(zg);
                float ig = sigm_fast(zi);
                float fg = sigm_fast(zf);
                float og = sigm_fast(zo);
                creg[q] = g * ig + creg[q] * fg;
                float hn = tanh_fast(creg[q]) * og;
                hb[q] = bf16_bits(hn);
                if (t == T - 1) hfin[(j0 + jl) * B + (b0 + nn)] = hn;
            }
            // h store: rows j0+2aa, j0+2aa+1 -> one 4-B store (same octet).
            const unsigned val = (unsigned)hb[0] | ((unsigned)hb[1] << 16);
            const int jj = j0 + 2 * aa;
            short* fb = (short*)(frag + ((t + 1) & 1) * 524288) + bt * 32768;
            short* fdst = fb + (jj >> 4) * 512 + ((jj >> 3) & 1) * 256
                        + nn * 8 + (jj & 7);
            if (lcl) {
                // genuine write-back L2 store (round-16, proven)
                __asm__ volatile("global_store_dword %0, %1, off"
                                 :: "v"(fdst), "v"(val) : "memory");
            } else {
                __hip_atomic_store((unsigned*)fdst, val, __ATOMIC_RELAXED,
                                   __HIP_MEMORY_SCOPE_AGENT);
            }
        }

        // ---- per-wave arrive (round-18 change): each wave drains its OWN
        // h-stores, then lane 0 stores its wave-flag (IC, sc1 — proven path).
        // No barrier before the flag: it departs while other waves finish.
        __asm__ volatile("s_waitcnt vmcnt(0)" ::: "memory");
        if (lane == 0) {
            __hip_atomic_store(myflag, (unsigned)(t + 1), __ATOMIC_RELAXED,
                               __HIP_MEMORY_SCOPE_AGENT);
        }
        // zb WAR: next step's zb writes must not race this step's reads
        __syncthreads();
    }
}

// ---------------- projection + softmax over batch --------------------------
__global__ __launch_bounds__(256) void lstm_final(
    const float* __restrict__ Wph, const float* __restrict__ hfin,
    const float* __restrict__ bp, float* __restrict__ out)
{
    __shared__ float sh[256];
    __shared__ float shm, shs;
    int c = blockIdx.x;
    int b = threadIdx.x;
    float acc = bp[b];
    const float* wr = Wph + c * H;
    for (int k = 0; k < H; ++k)
        acc += wr[k] * hfin[k * B + b];

    sh[b] = acc;
    __syncthreads();
    for (int s = 128; s > 0; s >>= 1) {
        if (b < s) sh[b] = fmaxf(sh[b], sh[b + s]);
        __syncthreads();
    }
    if (b == 0) shm = sh[0];
    __syncthreads();
    float e = expf(acc - shm);
    sh[b] = e;
    __syncthreads();
    for (int s = 128; s > 0; s >>= 1) {
        if (b < s) sh[b] += sh[b + s];
        __syncthreads();
    }
    if (b == 0) shs = sh[0];
    __syncthreads();
    out[b * NCLS + c] = e / shs;
}

extern "C" void kernel_launch(void* const* d_in, const int* in_sizes, int n_in,
                              void* d_out, int out_size, void* d_ws, size_t ws_size,
                              hipStream_t stream)
{
    const float* x   = (const float*)d_in[0];
    const float* Wgx = (const float*)d_in[1];
    const float* Wgh = (const float*)d_in[2];
    const float* Wix = (const float*)d_in[3];
    const float* Wih = (const float*)d_in[4];
    const float* Wfx = (const float*)d_in[5];
    const float* Wfh = (const float*)d_in[6];
    const float* Wox = (const float*)d_in[7];
    const float* Woh = (const float*)d_in[8];
    const float* Wph = (const float*)d_in[9];
    const float* bg  = (const float*)d_in[10];
    const float* bi  = (const float*)d_in[11];
    const float* bfv = (const float*)d_in[12];
    const float* bo  = (const float*)d_in[13];
    const float* bp  = (const float*)d_in[14];

    char* ws = (char*)d_ws;
    char* frag = ws;                                 // 1 MB (2 x 512 KB)
    unsigned* flags = (unsigned*)(ws + 1048576);     // 32 KB (256 x 128 B)
    unsigned* det   = (unsigned*)(ws + 1081344);     // 4 KB (256 x 4 B)
    float* hfin = (float*)(ws + 1085440);            // 1 MB

    // flags+det zeroed via IC-visible memset; frag needs no init (t=0 skip)
    hipMemsetAsync(flags, 0, 36864, stream);

    lstm_persist<<<256, 512, 0, stream>>>(
        x, Wgh, Wih, Wfh, Woh, Wgx, Wix, Wfx, Wox,
        bg, bi, bfv, bo, frag, flags, det, hfin);

    lstm_final<<<NCLS, 256, 0, stream>>>(Wph, hfin, bp, (float*)d_out);
}

// Round 8
// 1144.043 us; speedup vs baseline: 1.2478x; 1.2478x over previous
//
#include <hip/hip_runtime.h>
#include <hip/hip_bf16.h>

// LSTM H=1024, B=256, T=256, C=10 — round 19.
// Round 18 (per-wave flags) REGRESSED 1087->1412: consumer readiness became
// min-over-64 words; each wave's flag queued behind its own h-store drain so
// consumers observe max of 8 independent drain+IC latencies. The round-16
// barrier-then-one-flag arrive was overlapping those drains — reverted
// byte-identically. Round 19 keeps the ENTIRE round-16 protocol and changes
// only the wave->work mapping to kill the 2x redundant L2 read:
//  - waves = 8 k-eighths (K=128 each); each wave computes ALL 4 gates for
//    its eighth: one B-frag load feeds 4 MFMAs (was 2), block reads exactly
//    its unique 64 KB/step from L2 (was 128 KB; ~2.3k cyc/step -> ~1.1k).
//  - regs: awreg[4][8] = 128 AGPR (same), acc 4x f32x16 = 64 VGPR (+32)
//    offset by B-frags in flight 8 (was 16) = 32 VGPR (-32). Still ~256/wave.
//  - zb -> 32 planes (128 KB LDS, 1 block/CU so it fits); epilogue sums 8.
//  - per-wave poll shrinks to 4 producers (jt in [4ke,4ke+4)); union over
//    8 waves still covers all 32 peers -> WAR barrier-gate proof unchanged.
// Prediction: dur 1087 -> ~950-1010; MfmaUtil ~24%; WRITE ~4.1MB unchanged;
// VGPR_Count <= ~160 (higher => spill risk materialized). Flat -> L2 BW was
// not on the chain -> pivot to 2-groups/CU TLP.

#define H 1024
#define B 256
#define T 256
#define NCLS 10

typedef __attribute__((ext_vector_type(8))) short short8;   // 8 bf16
typedef __attribute__((ext_vector_type(2))) float f32x2;
typedef __attribute__((ext_vector_type(4))) float f32x4;
typedef __attribute__((ext_vector_type(16))) float f32x16;

__device__ inline unsigned short bf16_bits(float f) {
    union { __hip_bfloat16 h; unsigned short u; } cv;
    cv.h = __float2bfloat16(f);
    return cv.u;
}

#define L2E 1.4426950408889634f
__device__ inline float sigm_fast(float x) {
    float e = __builtin_amdgcn_exp2f(-L2E * x);
    return __builtin_amdgcn_rcpf(1.0f + e);
}
__device__ inline float tanh_fast(float x) {
    float e = __builtin_amdgcn_exp2f((2.0f * L2E) * x);     // e^(2x)
    return 1.0f - 2.0f * __builtin_amdgcn_rcpf(1.0f + e);   // +-sat correct
}

// h frag layout (per 512 KB buffer), 32x32x16 B-frag order, per bt-slice:
//   short index of (j in [0,1024), b-in-slice nn in [0,32)):
//   bt*32768 + (j>>4)*512 + ((j>>3)&1)*256 + nn*8 + (j&7)
// Wave ke's eighth = bytes [ke*8192, +8192) of the bt-slice; kstep c at
// byte ke*8192 + c*1024 + lane*16 == the 32x32x16 B-frag for that kstep.

#define LOADS4(d0, d1, d2, d3, PTR, SC)                                   \
    __asm__ volatile(                                                     \
        "global_load_dwordx4 %0, %4, off " SC "\n\t"                      \
        "global_load_dwordx4 %1, %4, off offset:1024 " SC "\n\t"          \
        "global_load_dwordx4 %2, %4, off offset:2048 " SC "\n\t"          \
        "global_load_dwordx4 %3, %4, off offset:3072 " SC                  \
        : "=&v"(d0), "=&v"(d1), "=&v"(d2), "=&v"(d3)                      \
        : "v"(PTR));

#define WAIT4(N, d0, d1, d2, d3)                                          \
    __asm__ volatile("s_waitcnt vmcnt(" N ")"                             \
        : "+v"(d0), "+v"(d1), "+v"(d2), "+v"(d3));

#define MM4(c, bb)                                                        \
    a0 = __builtin_amdgcn_mfma_f32_32x32x16_bf16(awreg[0][c], bb, a0, 0, 0, 0); \
    a1 = __builtin_amdgcn_mfma_f32_32x32x16_bf16(awreg[1][c], bb, a1, 0, 0, 0); \
    a2 = __builtin_amdgcn_mfma_f32_32x32x16_bf16(awreg[2][c], bb, a2, 0, 0, 0); \
    a3 = __builtin_amdgcn_mfma_f32_32x32x16_bf16(awreg[3][c], bb, a3, 0, 0, 0);

#define GATE_MFMA8(SC)                                                    \
    {                                                                     \
        short8 b0, b1, b2, b3, b4, b5, b6, b7;                            \
        LOADS4(b0, b1, b2, b3, gb, SC)                                    \
        LOADS4(b4, b5, b6, b7, gb + 4096, SC)                             \
        WAIT4("4", b0, b1, b2, b3)                                        \
        MM4(0, b0) MM4(1, b1) MM4(2, b2) MM4(3, b3)                       \
        WAIT4("0", b4, b5, b6, b7)                                        \
        MM4(4, b4) MM4(5, b5) MM4(6, b6) MM4(7, b7)                       \
    }

__global__ __launch_bounds__(512)
__attribute__((amdgpu_waves_per_eu(2, 2)))
void lstm_persist(
    const float* __restrict__ x,
    const float* __restrict__ Wgh, const float* __restrict__ Wih,
    const float* __restrict__ Wfh, const float* __restrict__ Woh,
    const float* __restrict__ Wgx, const float* __restrict__ Wix,
    const float* __restrict__ Wfx, const float* __restrict__ Wox,
    const float* __restrict__ bg, const float* __restrict__ bi,
    const float* __restrict__ bf_, const float* __restrict__ bo,
    char* __restrict__ frag,            // 2 x 524288 bytes (NOT pre-zeroed)
    unsigned* __restrict__ flags,       // 256 flag lines, 128-B stride (IC)
    unsigned* __restrict__ det,         // 256 slots x 4B (IC), zeroed
    float* __restrict__ hfin)           // H x B fp32
{
    __shared__ __align__(16) float zb[32][32][32]; // [ke*4+g][col][swz rows]
    __shared__ float wxl[4][32];
    __shared__ float bsl[4][32];
    __shared__ int sh_lcl;

    const int tid  = threadIdx.x;
    const int lane = tid & 63;
    const int ke   = tid >> 6;          // k-eighth, 0..7 (128 of K=1024)
    const int bt = blockIdx.x & 7;      // work mapping == round 11 (unchanged)
    const int jt = blockIdx.x >> 3;
    const int j0 = jt * 32;
    const int b0 = bt * 32;

    // ---- one-time: publish my physical XCD id to my group's det slot ----
    unsigned xcc;
    __asm__ volatile("s_getreg_b32 %0, hwreg(HW_REG_XCC_ID)" : "=s"(xcc));
    xcc &= 7u;
    if (tid == 0)
        __hip_atomic_store(&det[bt * 32 + jt], xcc + 1u,
                           __ATOMIC_RELAXED, __HIP_MEMORY_SCOPE_AGENT);

    if (tid < 128) {
        int g = tid >> 5, r = tid & 31;
        const float* wx = (g == 0) ? Wgx : (g == 1) ? Wix : (g == 2) ? Wfx : Wox;
        const float* bb = (g == 0) ? bg  : (g == 1) ? bi  : (g == 2) ? bf_ : bo;
        wxl[g][r] = wx[j0 + r];
        bsl[g][r] = bb[b0 + r];
    }

    // ---- one-time: W tiles -> registers, 32x32x16 A-fragment order ----
    // (verified): row = lane&31, k = (lane>>5)*8 + e. Wave ke covers
    // K [ke*128, ke*128+128) = 8 ksteps, ALL 4 gates.
    const float* Wptr[4] = {Wgh, Wih, Wfh, Woh};
    short8 awreg[4][8];
#pragma unroll
    for (int g = 0; g < 4; ++g) {
        const float* wrow = Wptr[g] + (j0 + (lane & 31)) * H
                          + ke * 128 + ((lane >> 5) * 8);
#pragma unroll
        for (int c = 0; c < 8; ++c) {
            const float4 f0 = *(const float4*)(wrow + c * 16);
            const float4 f1 = *(const float4*)(wrow + c * 16 + 4);
            short8 s;
            s[0] = (short)bf16_bits(f0.x); s[1] = (short)bf16_bits(f0.y);
            s[2] = (short)bf16_bits(f0.z); s[3] = (short)bf16_bits(f0.w);
            s[4] = (short)bf16_bits(f1.x); s[5] = (short)bf16_bits(f1.y);
            s[6] = (short)bf16_bits(f1.z); s[7] = (short)bf16_bits(f1.w);
            awreg[g][c] = s;
        }
    }
#pragma unroll
    for (int g = 0; g < 4; ++g)
#pragma unroll
        for (int c = 0; c < 8; ++c)
            __asm__ volatile("" : "+a"(awreg[g][c]));

    // ---- one-time: group locality verdict (poll my group's 32 det slots) ----
    if (tid < 64) {
        unsigned v;
        while (true) {
            v = __hip_atomic_load(&det[bt * 32 + (lane & 31)],
                                  __ATOMIC_RELAXED, __HIP_MEMORY_SCOPE_AGENT);
            if (__all((int)(v != 0u))) break;
            __builtin_amdgcn_s_sleep(1);
        }
        int same = __all((int)(v == xcc + 1u));
        if (tid == 0) sh_lcl = same;
    }
    __syncthreads();
    const bool lcl = (sh_lcl != 0);

    float creg[2] = {0.f, 0.f};
    const int nn = tid & 31;
    const int aa = tid >> 5;            // 0..15: rows 2aa, 2aa+1

    unsigned* myflag = &flags[blockIdx.x * 32];
    // per-wave poll set: the 4 producers of my k-eighth (jt' = 4ke+(lane&3))
    unsigned* pollflag = &flags[(((ke << 2) + (lane & 3)) * 8 + bt) * 32];

    for (int t = 0; t < T; ++t) {
        const float xv = x[(b0 + nn) * T + t];

        f32x16 a0 = {0.f,0.f,0.f,0.f,0.f,0.f,0.f,0.f,
                     0.f,0.f,0.f,0.f,0.f,0.f,0.f,0.f};
        f32x16 a1 = a0, a2 = a0, a3 = a0;

        if (t > 0) {        // h_0 == 0 -> z == 0: skip poll+loads+MFMA at t=0
            // ---- per-wave wait on my 4 producers (round-16 IC protocol) ----
            {
                const unsigned target = (unsigned)t;
                while (true) {
                    unsigned v = __hip_atomic_load(pollflag, __ATOMIC_RELAXED,
                                                   __HIP_MEMORY_SCOPE_AGENT);
                    if (__all((int)(v >= target))) break;
                    __builtin_amdgcn_s_sleep(1);
                }
            }
            // force xv retired so vmcnt counts below are exact
            __asm__ volatile("" :: "v"(xv));

            // ---- B-frags direct from global, counted-vmcnt MFMA ----
            const char* gb = frag + (t & 1) * 524288 + bt * 65536
                           + (ke << 13) + lane * 16;
            if (lcl) {       // XCD-local exchange: L2 hit (L1 bypass only)
                GATE_MFMA8("sc0")
            } else {         // cross-XCD: IC path (round-11 semantics)
                GATE_MFMA8("sc0 sc1")
            }
        }

        // C/D (HW-verified 32x32): col = lane&31,
        // row = (reg&3) + 8*(reg>>2) + 4*(lane>>5) = 4*grp + e, grp=2*rq+hi.
        // zb float idx: ((ke*4+g)<<10) + (col<<5) + ((grp^(col&7))<<2) + e.
        {
            float* zbF = &zb[0][0][0];
            const int col = lane & 31;
            const int hi  = lane >> 5;
#pragma unroll
            for (int rq = 0; rq < 4; ++rq) {
                const int sw = ((2 * rq + hi) ^ (col & 7)) << 2;
                f32x4 w0, w1, w2, w3;
#pragma unroll
                for (int e = 0; e < 4; ++e) {
                    w0[e] = a0[rq * 4 + e];
                    w1[e] = a1[rq * 4 + e];
                    w2[e] = a2[rq * 4 + e];
                    w3[e] = a3[rq * 4 + e];
                }
                const int pb = (ke << 2);
                *(f32x4*)(zbF + ((pb + 0) << 10) + (col << 5) + sw) = w0;
                *(f32x4*)(zbF + ((pb + 1) << 10) + (col << 5) + sw) = w1;
                *(f32x4*)(zbF + ((pb + 2) << 10) + (col << 5) + sw) = w2;
                *(f32x4*)(zbF + ((pb + 3) << 10) + (col << 5) + sw) = w3;
            }
        }
        __syncthreads();   // all waves' polls done => all 32 peers >= t:
                           // stores below cannot overwrite a peer's live read

        // ---- elementwise epilogue: 512 threads x 2 rows (f32x2 zb reads) ----
        {
            const int grp = aa >> 1, half = aa & 1;  // rows 4grp+2half+{0,1}
            const float* zcol = &zb[0][0][0] + (nn << 5);
            const int fo = ((grp ^ (nn & 7)) << 2) + (half << 1);
            f32x2 zs[4];
#pragma unroll
            for (int gi = 0; gi < 4; ++gi) {
                f32x2 s = *(const f32x2*)(zcol + (gi << 10) + fo);
#pragma unroll
                for (int kk = 1; kk < 8; ++kk)
                    s += *(const f32x2*)(zcol + (((kk << 2) + gi) << 10) + fo);
                zs[gi] = s;
            }
            unsigned short hb[2];
#pragma unroll
            for (int q = 0; q < 2; ++q) {
                const int jl = 2 * aa + q;
                float zg = zs[0][q] + wxl[0][jl] * xv + bsl[0][nn];
                float zi = zs[1][q] + wxl[1][jl] * xv + bsl[1][nn];
                float zf = zs[2][q] + wxl[2][jl] * xv + bsl[2][nn];
                float zo = zs[3][q] + wxl[3][jl] * xv + bsl[3][nn];
                float g  = tanh_fast(zg);
                float ig = sigm_fast(zi);
                float fg = sigm_fast(zf);
                float og = sigm_fast(zo);
                creg[q] = g * ig + creg[q] * fg;
                float hn = tanh_fast(creg[q]) * og;
                hb[q] = bf16_bits(hn);
                if (t == T - 1) hfin[(j0 + jl) * B + (b0 + nn)] = hn;
            }
            // h store: rows j0+2aa, j0+2aa+1 -> one 4-B store (same octet).
            const unsigned val = (unsigned)hb[0] | ((unsigned)hb[1] << 16);
            const int jj = j0 + 2 * aa;
            short* fb = (short*)(frag + ((t + 1) & 1) * 524288) + bt * 32768;
            short* fdst = fb + (jj >> 4) * 512 + ((jj >> 3) & 1) * 256
                        + nn * 8 + (jj & 7);
            if (lcl) {
                // genuine write-back L2 store (round-16, proven)
                __asm__ volatile("global_store_dword %0, %1, off"
                                 :: "v"(fdst), "v"(val) : "memory");
            } else {
                __hip_atomic_store((unsigned*)fdst, val, __ATOMIC_RELAXED,
                                   __HIP_MEMORY_SCOPE_AGENT);
            }
        }

        // ---- arrive (round-16, proven): barrier drains every wave's
        // store-acks (compiler emits vmcnt(0) before s_barrier), then one
        // IC flag store ----
        __syncthreads();
        if (tid == 0) {
            __asm__ volatile("s_waitcnt vmcnt(0)" ::: "memory");
            __hip_atomic_store(myflag, (unsigned)(t + 1), __ATOMIC_RELAXED,
                               __HIP_MEMORY_SCOPE_AGENT);
        }
    }
}

// ---------------- projection + softmax over batch --------------------------
__global__ __launch_bounds__(256) void lstm_final(
    const float* __restrict__ Wph, const float* __restrict__ hfin,
    const float* __restrict__ bp, float* __restrict__ out)
{
    __shared__ float sh[256];
    __shared__ float shm, shs;
    int c = blockIdx.x;
    int b = threadIdx.x;
    float acc = bp[b];
    const float* wr = Wph + c * H;
    for (int k = 0; k < H; ++k)
        acc += wr[k] * hfin[k * B + b];

    sh[b] = acc;
    __syncthreads();
    for (int s = 128; s > 0; s >>= 1) {
        if (b < s) sh[b] = fmaxf(sh[b], sh[b + s]);
        __syncthreads();
    }
    if (b == 0) shm = sh[0];
    __syncthreads();
    float e = expf(acc - shm);
    sh[b] = e;
    __syncthreads();
    for (int s = 128; s > 0; s >>= 1) {
        if (b < s) sh[b] += sh[b + s];
        __syncthreads();
    }
    if (b == 0) shs = sh[0];
    __syncthreads();
    out[b * NCLS + c] = e / shs;
}

extern "C" void kernel_launch(void* const* d_in, const int* in_sizes, int n_in,
                              void* d_out, int out_size, void* d_ws, size_t ws_size,
                              hipStream_t stream)
{
    const float* x   = (const float*)d_in[0];
    const float* Wgx = (const float*)d_in[1];
    const float* Wgh = (const float*)d_in[2];
    const float* Wix = (const float*)d_in[3];
    const float* Wih = (const float*)d_in[4];
    const float* Wfx = (const float*)d_in[5];
    const float* Wfh = (const float*)d_in[6];
    const float* Wox = (const float*)d_in[7];
    const float* Woh = (const float*)d_in[8];
    const float* Wph = (const float*)d_in[9];
    const float* bg  = (const float*)d_in[10];
    const float* bi  = (const float*)d_in[11];
    const float* bfv = (const float*)d_in[12];
    const float* bo  = (const float*)d_in[13];
    const float* bp  = (const float*)d_in[14];

    char* ws = (char*)d_ws;
    char* frag = ws;                                 // 1 MB (2 x 512 KB)
    unsigned* flags = (unsigned*)(ws + 1048576);     // 32 KB (256 x 128 B)
    unsigned* det   = (unsigned*)(ws + 1081344);     // 4 KB (256 x 4 B)
    float* hfin = (float*)(ws + 1085440);            // 1 MB

    // flags+det zeroed via IC-visible memset; frag needs no init (t=0 skip)
    hipMemsetAsync(flags, 0, 36864, stream);

    lstm_persist<<<256, 512, 0, stream>>>(
        x, Wgh, Wih, Wfh, Woh, Wgx, Wix, Wfx, Wox,
        bg, bi, bfv, bo, frag, flags, det, hfin);

    lstm_final<<<NCLS, 256, 0, stream>>>(Wph, hfin, bp, (float*)d_out);
}

// Round 9
// 1142.224 us; speedup vs baseline: 1.2498x; 1.0016x over previous
//
#include <hip/hip_runtime.h>
#include <hip/hip_bf16.h>

// LSTM H=1024, B=256, T=256, C=10 — round 20.
// r19 (4x B-reuse) regressed 1087->1137: saved L2 traffic was overlapped
// (free) while the doubled epilogue partial-sum (16->32 LDS reads, 2.5x
// conflicts) was serial-after-barrier (expensive). Rounds 14-19 pattern:
// only serial chain segments and rendezvous legs move dur. Round 20 =
// round 16 EXACT revert (proven 1087) + two chain trims that touch no
// store path:
//  1) pipelined poll: two outstanding sc0sc1 flag loads staggered by
//     s_sleep 2, checked at vmcnt(1)/vmcnt(0) -> check interval ~800cy
//     -> ~450cy, detect lag -200-350cy/step. Read-only change.
//  2) x -> LDS prefetch (one-time 32KB, xl[t][b]): per-step xv becomes an
//     LDS broadcast read; removes the 32-line global x read from the step
//     head. LDS ~99KB, still 1 block/CU.
// Prediction: dur -> ~1020-1060; FETCH 73.6->~40MB (trim-2 signature);
// WRITE 4.1MB unchanged; conflicts ~3.4e7; VGPR ~128. If flat (>=1080):
// chain is pinned by the sc1/IC flag round-trip (untouchable after 2
// container kills) -> structural floor, write it up.

#define H 1024
#define B 256
#define T 256
#define NCLS 10

typedef __attribute__((ext_vector_type(8))) short short8;   // 8 bf16
typedef __attribute__((ext_vector_type(2))) float f32x2;
typedef __attribute__((ext_vector_type(4))) float f32x4;
typedef __attribute__((ext_vector_type(16))) float f32x16;

__device__ inline unsigned short bf16_bits(float f) {
    union { __hip_bfloat16 h; unsigned short u; } cv;
    cv.h = __float2bfloat16(f);
    return cv.u;
}

#define L2E 1.4426950408889634f
__device__ inline float sigm_fast(float x) {
    float e = __builtin_amdgcn_exp2f(-L2E * x);
    return __builtin_amdgcn_rcpf(1.0f + e);
}
__device__ inline float tanh_fast(float x) {
    float e = __builtin_amdgcn_exp2f((2.0f * L2E) * x);     // e^(2x)
    return 1.0f - 2.0f * __builtin_amdgcn_rcpf(1.0f + e);   // +-sat correct
}

// h frag layout (per 512 KB buffer), 32x32x16 B-frag order, per bt-slice:
//   short index of (j in [0,1024), b-in-slice nn in [0,32)):
//   bt*32768 + (j>>4)*512 + ((j>>3)&1)*256 + nn*8 + (j&7)
// Wave kq's quarter = bytes [kq*16384, +16384) of the bt-slice; kstep c at
// byte kq*16384 + c*1024 + lane*16 == the 32x32x16 B-frag for that kstep.

#define LOADS4(d0, d1, d2, d3, PTR, SC)                                   \
    __asm__ volatile(                                                     \
        "global_load_dwordx4 %0, %4, off " SC "\n\t"                      \
        "global_load_dwordx4 %1, %4, off offset:1024 " SC "\n\t"          \
        "global_load_dwordx4 %2, %4, off offset:2048 " SC "\n\t"          \
        "global_load_dwordx4 %3, %4, off offset:3072 " SC                  \
        : "=&v"(d0), "=&v"(d1), "=&v"(d2), "=&v"(d3)                      \
        : "v"(PTR));

#define WAIT4(N, d0, d1, d2, d3)                                          \
    __asm__ volatile("s_waitcnt vmcnt(" N ")"                             \
        : "+v"(d0), "+v"(d1), "+v"(d2), "+v"(d3));

#define MM(c, bb)                                                         \
    acc0 = __builtin_amdgcn_mfma_f32_32x32x16_bf16(awreg[0][c], bb, acc0, 0, 0, 0); \
    acc1 = __builtin_amdgcn_mfma_f32_32x32x16_bf16(awreg[1][c], bb, acc1, 0, 0, 0);

#define GATE_MFMA(SC)                                                     \
    {                                                                     \
        short8 b0, b1, b2, b3, b4, b5, b6, b7;                            \
        short8 b8, b9, b10, b11, b12, b13, b14, b15;                      \
        LOADS4(b0, b1, b2, b3, gb, SC)                                    \
        LOADS4(b4, b5, b6, b7, gb + 4096, SC)                             \
        WAIT4("4", b0, b1, b2, b3)                                        \
        MM(0, b0) MM(1, b1) MM(2, b2) MM(3, b3)                           \
        LOADS4(b8, b9, b10, b11, gb + 8192, SC)                           \
        LOADS4(b12, b13, b14, b15, gb + 12288, SC)                        \
        WAIT4("8", b4, b5, b6, b7)                                        \
        MM(4, b4) MM(5, b5) MM(6, b6) MM(7, b7)                           \
        WAIT4("4", b8, b9, b10, b11)                                      \
        MM(8, b8) MM(9, b9) MM(10, b10) MM(11, b11)                       \
        WAIT4("0", b12, b13, b14, b15)                                    \
        MM(12, b12) MM(13, b13) MM(14, b14) MM(15, b15)                   \
    }

__global__ __launch_bounds__(512)
__attribute__((amdgpu_waves_per_eu(2, 2)))
void lstm_persist(
    const float* __restrict__ x,
    const float* __restrict__ Wgh, const float* __restrict__ Wih,
    const float* __restrict__ Wfh, const float* __restrict__ Woh,
    const float* __restrict__ Wgx, const float* __restrict__ Wix,
    const float* __restrict__ Wfx, const float* __restrict__ Wox,
    const float* __restrict__ bg, const float* __restrict__ bi,
    const float* __restrict__ bf_, const float* __restrict__ bo,
    char* __restrict__ frag,            // 2 x 524288 bytes (NOT pre-zeroed)
    unsigned* __restrict__ flags,       // 256 flag lines, 128-B stride (IC)
    unsigned* __restrict__ det,         // 256 slots x 4B (IC), zeroed
    float* __restrict__ hfin)           // H x B fp32
{
    __shared__ __align__(16) float zb[16][32][32]; // [kq*4+g][col][swz rows]
    __shared__ __align__(16) float xl[T][32];      // x slice [t][b] (32 KB)
    __shared__ float wxl[4][32];
    __shared__ float bsl[4][32];
    __shared__ int sh_lcl;

    const int tid  = threadIdx.x;
    const int lane = tid & 63;
    const int wave = tid >> 6;          // 0..7
    const int gp   = wave >> 2;         // gate pair: 0 -> {g,i}, 1 -> {f,o}
    const int kq   = wave & 3;          // k-quarter (256 of K=1024)
    const int bt = blockIdx.x & 7;      // work mapping == round 11 (unchanged)
    const int jt = blockIdx.x >> 3;
    const int j0 = jt * 32;
    const int b0 = bt * 32;

    // ---- one-time: publish my physical XCD id to my group's det slot ----
    unsigned xcc;
    __asm__ volatile("s_getreg_b32 %0, hwreg(HW_REG_XCC_ID)" : "=s"(xcc));
    xcc &= 7u;
    if (tid == 0)
        __hip_atomic_store(&det[bt * 32 + jt], xcc + 1u,
                           __ATOMIC_RELAXED, __HIP_MEMORY_SCOPE_AGENT);

    if (tid < 128) {
        int g = tid >> 5, r = tid & 31;
        const float* wx = (g == 0) ? Wgx : (g == 1) ? Wix : (g == 2) ? Wfx : Wox;
        const float* bb = (g == 0) ? bg  : (g == 1) ? bi  : (g == 2) ? bf_ : bo;
        wxl[g][r] = wx[j0 + r];
        bsl[g][r] = bb[b0 + r];
    }

    // ---- one-time: x slice -> LDS, xl[t][b] (round-20 trim 2) ----
    {
        const int row = tid & 31;            // b-in-slice
        const int t0  = (tid >> 5) * 16;     // 16 t-values per thread
        const float* xrow = x + (b0 + row) * T + t0;
#pragma unroll
        for (int i = 0; i < 16; i += 4) {
            const float4 f = *(const float4*)(xrow + i);
            xl[t0 + i + 0][row] = f.x;
            xl[t0 + i + 1][row] = f.y;
            xl[t0 + i + 2][row] = f.z;
            xl[t0 + i + 3][row] = f.w;
        }
    }

    // ---- one-time: W tiles -> registers, 32x32x16 A-fragment order ----
    // (verified by round-14 pass): row = lane&31, k = (lane>>5)*8 + e.
    const float* Wlo = (gp == 0) ? Wgh : Wfh;
    const float* Whi = (gp == 0) ? Wih : Woh;
    short8 awreg[2][16];
#pragma unroll
    for (int gg = 0; gg < 2; ++gg) {
        const float* Wp = gg ? Whi : Wlo;
        const float* wrow = Wp + (j0 + (lane & 31)) * H
                          + kq * 256 + ((lane >> 5) * 8);
#pragma unroll
        for (int c = 0; c < 16; ++c) {
            const float4 f0 = *(const float4*)(wrow + c * 16);
            const float4 f1 = *(const float4*)(wrow + c * 16 + 4);
            short8 s;
            s[0] = (short)bf16_bits(f0.x); s[1] = (short)bf16_bits(f0.y);
            s[2] = (short)bf16_bits(f0.z); s[3] = (short)bf16_bits(f0.w);
            s[4] = (short)bf16_bits(f1.x); s[5] = (short)bf16_bits(f1.y);
            s[6] = (short)bf16_bits(f1.z); s[7] = (short)bf16_bits(f1.w);
            awreg[gg][c] = s;
        }
    }
#pragma unroll
    for (int gg = 0; gg < 2; ++gg)
#pragma unroll
        for (int c = 0; c < 16; ++c)
            __asm__ volatile("" : "+a"(awreg[gg][c]));

    // ---- one-time: group locality verdict (poll my group's 32 det slots) ----
    if (wave == 0) {
        unsigned v;
        while (true) {
            v = __hip_atomic_load(&det[bt * 32 + (lane & 31)],
                                  __ATOMIC_RELAXED, __HIP_MEMORY_SCOPE_AGENT);
            if (__all((int)(v != 0u))) break;
            __builtin_amdgcn_s_sleep(1);
        }
        int same = __all((int)(v == xcc + 1u));
        if (tid == 0) sh_lcl = same;
    }
    __syncthreads();
    const bool lcl = (sh_lcl != 0);

    float creg[2] = {0.f, 0.f};
    const int nn = tid & 31;
    const int aa = tid >> 5;            // 0..15: rows 2aa, 2aa+1

    unsigned* myflag = &flags[blockIdx.x * 32];
    // per-wave poll set: only the 8 producers of my k-quarter
    unsigned* pollflag = &flags[(((kq << 3) + (lane & 7)) * 8 + bt) * 32];

    for (int t = 0; t < T; ++t) {
        const float xv = xl[t][nn];     // LDS broadcast (round-20 trim 2)

        f32x16 acc0 = {0.f,0.f,0.f,0.f,0.f,0.f,0.f,0.f,
                       0.f,0.f,0.f,0.f,0.f,0.f,0.f,0.f};
        f32x16 acc1 = acc0;

        if (t > 0) {        // h_0 == 0 -> z == 0: skip poll+loads+MFMA at t=0
            // ---- pipelined poll (round-20 trim 1): two staggered
            // outstanding sc0sc1 loads, checks ~450cy apart. Read-only. ----
            {
                const unsigned target = (unsigned)t;
                while (true) {
                    unsigned a, b;
                    __asm__ volatile(
                        "global_load_dword %0, %2, off sc0 sc1\n\t"
                        "s_sleep 2\n\t"
                        "global_load_dword %1, %2, off sc0 sc1\n\t"
                        "s_waitcnt vmcnt(1)"
                        : "=&v"(a), "=&v"(b) : "v"(pollflag) : "memory");
                    if (__all((int)(a >= target))) {
                        __asm__ volatile("s_waitcnt vmcnt(0)" ::: "memory");
                        break;
                    }
                    __asm__ volatile("s_waitcnt vmcnt(0)" : "+v"(b) :: "memory");
                    if (__all((int)(b >= target))) break;
                    __builtin_amdgcn_s_sleep(1);
                }
            }
            // vmcnt == 0 here (both poll loads retired) -> GATE counts exact

            // ---- B-frags direct from global, counted-vmcnt MFMA ----
            const char* gb = frag + (t & 1) * 524288 + bt * 65536
                           + (kq << 14) + lane * 16;
            if (lcl) {       // XCD-local exchange: L2 hit (L1 bypass only)
                GATE_MFMA("sc0")
            } else {         // cross-XCD: IC path (round-11 semantics)
                GATE_MFMA("sc0 sc1")
            }
        }

        // C/D (HW-verified 32x32): col = lane&31,
        // row = (reg&3) + 8*(reg>>2) + 4*(lane>>5) = 4*grp + e, grp=2*rq+hi.
        // zb float idx: ((kq*4+g)<<10) + (col<<5) + ((grp^(col&7))<<2) + e.
        {
            float* zbF = &zb[0][0][0];
            const int col = lane & 31;
            const int hi  = lane >> 5;
            const int g0 = gp * 2, g1 = g0 + 1;
#pragma unroll
            for (int rq = 0; rq < 4; ++rq) {
                const int sw = ((2 * rq + hi) ^ (col & 7)) << 2;
                f32x4 w0, w1;
#pragma unroll
                for (int e = 0; e < 4; ++e) {
                    w0[e] = acc0[rq * 4 + e];
                    w1[e] = acc1[rq * 4 + e];
                }
                *(f32x4*)(zbF + ((kq * 4 + g0) << 10) + (col << 5) + sw) = w0;
                *(f32x4*)(zbF + ((kq * 4 + g1) << 10) + (col << 5) + sw) = w1;
            }
        }
        __syncthreads();   // all waves' polls done => all 32 peers >= t:
                           // stores below cannot overwrite a peer's live read

        // ---- elementwise epilogue: 512 threads x 2 rows (f32x2 zb reads) ----
        {
            const int grp = aa >> 1, half = aa & 1;  // rows 4grp+2half+{0,1}
            const float* zcol = &zb[0][0][0] + (nn << 5);
            const int fo = ((grp ^ (nn & 7)) << 2) + (half << 1);
            f32x2 zs[4];
#pragma unroll
            for (int gi = 0; gi < 4; ++gi) {
                f32x2 s = *(const f32x2*)(zcol + (gi << 10) + fo);
#pragma unroll
                for (int kk = 1; kk < 4; ++kk)
                    s += *(const f32x2*)(zcol + (((kk << 2) + gi) << 10) + fo);
                zs[gi] = s;
            }
            unsigned short hb[2];
#pragma unroll
            for (int q = 0; q < 2; ++q) {
                const int jl = 2 * aa + q;
                float zg = zs[0][q] + wxl[0][jl] * xv + bsl[0][nn];
                float zi = zs[1][q] + wxl[1][jl] * xv + bsl[1][nn];
                float zf = zs[2][q] + wxl[2][jl] * xv + bsl[2][nn];
                float zo = zs[3][q] + wxl[3][jl] * xv + bsl[3][nn];
                float g  = tanh_fast(zg);
                float ig = sigm_fast(zi);
                float fg = sigm_fast(zf);
                float og = sigm_fast(zo);
                creg[q] = g * ig + creg[q] * fg;
                float hn = tanh_fast(creg[q]) * og;
                hb[q] = bf16_bits(hn);
                if (t == T - 1) hfin[(j0 + jl) * B + (b0 + nn)] = hn;
            }
            // h store: rows j0+2aa, j0+2aa+1 -> one 4-B store (same octet).
            const unsigned val = (unsigned)hb[0] | ((unsigned)hb[1] << 16);
            const int jj = j0 + 2 * aa;
            short* fb = (short*)(frag + ((t + 1) & 1) * 524288) + bt * 32768;
            short* fdst = fb + (jj >> 4) * 512 + ((jj >> 3) & 1) * 256
                        + nn * 8 + (jj & 7);
            if (lcl) {
                // genuine write-back L2 store (round-16, proven)
                __asm__ volatile("global_store_dword %0, %1, off"
                                 :: "v"(fdst), "v"(val) : "memory");
            } else {
                __hip_atomic_store((unsigned*)fdst, val, __ATOMIC_RELAXED,
                                   __HIP_MEMORY_SCOPE_AGENT);
            }
        }

        // ---- arrive (round-16, proven): barrier drains every wave's
        // store-acks, then one IC flag store ----
        __syncthreads();
        if (tid == 0) {
            __asm__ volatile("s_waitcnt vmcnt(0)" ::: "memory");
            __hip_atomic_store(myflag, (unsigned)(t + 1), __ATOMIC_RELAXED,
                               __HIP_MEMORY_SCOPE_AGENT);
        }
    }
}

// ---------------- projection + softmax over batch --------------------------
__global__ __launch_bounds__(256) void lstm_final(
    const float* __restrict__ Wph, const float* __restrict__ hfin,
    const float* __restrict__ bp, float* __restrict__ out)
{
    __shared__ float sh[256];
    __shared__ float shm, shs;
    int c = blockIdx.x;
    int b = threadIdx.x;
    float acc = bp[b];
    const float* wr = Wph + c * H;
    for (int k = 0; k < H; ++k)
        acc += wr[k] * hfin[k * B + b];

    sh[b] = acc;
    __syncthreads();
    for (int s = 128; s > 0; s >>= 1) {
        if (b < s) sh[b] = fmaxf(sh[b], sh[b + s]);
        __syncthreads();
    }
    if (b == 0) shm = sh[0];
    __syncthreads();
    float e = expf(acc - shm);
    sh[b] = e;
    __syncthreads();
    for (int s = 128; s > 0; s >>= 1) {
        if (b < s) sh[b] += sh[b + s];
        __syncthreads();
    }
    if (b == 0) shs = sh[0];
    __syncthreads();
    out[b * NCLS + c] = e / shs;
}

extern "C" void kernel_launch(void* const* d_in, const int* in_sizes, int n_in,
                              void* d_out, int out_size, void* d_ws, size_t ws_size,
                              hipStream_t stream)
{
    const float* x   = (const float*)d_in[0];
    const float* Wgx = (const float*)d_in[1];
    const float* Wgh = (const float*)d_in[2];
    const float* Wix = (const float*)d_in[3];
    const float* Wih = (const float*)d_in[4];
    const float* Wfx = (const float*)d_in[5];
    const float* Wfh = (const float*)d_in[6];
    const float* Wox = (const float*)d_in[7];
    const float* Woh = (const float*)d_in[8];
    const float* Wph = (const float*)d_in[9];
    const float* bg  = (const float*)d_in[10];
    const float* bi  = (const float*)d_in[11];
    const float* bfv = (const float*)d_in[12];
    const float* bo  = (const float*)d_in[13];
    const float* bp  = (const float*)d_in[14];

    char* ws = (char*)d_ws;
    char* frag = ws;                                 // 1 MB (2 x 512 KB)
    unsigned* flags = (unsigned*)(ws + 1048576);     // 32 KB (256 x 128 B)
    unsigned* det   = (unsigned*)(ws + 1081344);     // 4 KB (256 x 4 B)
    float* hfin = (float*)(ws + 1085440);            // 1 MB

    // flags+det zeroed via IC-visible memset; frag needs no init (t=0 skip)
    hipMemsetAsync(flags, 0, 36864, stream);

    lstm_persist<<<256, 512, 0, stream>>>(
        x, Wgh, Wih, Wfh, Woh, Wgx, Wix, Wfx, Wox,
        bg, bi, bfv, bo, frag, flags, det, hfin);

    lstm_final<<<NCLS, 256, 0, stream>>>(Wph, hfin, bp, (float*)d_out);
}